// Round 14
// baseline (128.779 us; speedup 1.0000x reference)
//
#include <hip/hip_runtime.h>
#include <hip/hip_bf16.h>
#include <hip/hip_fp16.h>

typedef _Float16 half8 __attribute__((ext_vector_type(8)));
typedef _Float16 half4 __attribute__((ext_vector_type(4)));
typedef float floatx4 __attribute__((ext_vector_type(4)));

#define BATCH   4096
#define NIN     1024
#define NODES   4095
#define NPAD    4096
#define NOUT    1024
#define NLEAF   4096
#define SPLITK  4

__device__ __forceinline__ void gload_lds16(const void* g, void* l) {
    __builtin_amdgcn_global_load_lds(
        (const __attribute__((address_space(1))) void*)g,
        (__attribute__((address_space(3))) void*)l, 16, 0, 0);
}

// ---------- convert f32 -> f16, zero-padding past nsrc ----------
__global__ void k_f32_to_f16_pad(const float* __restrict__ src,
                                 _Float16* __restrict__ dst, int n, int nsrc) {
    int i = (blockIdx.x * blockDim.x + threadIdx.x) * 4;
    if (i >= n) return;
    float4 v;
    if (i < nsrc) v = *(const float4*)(src + i);
    else          v = make_float4(0.f, 0.f, 0.f, 0.f);
    half4 h;
    h.x = (_Float16)v.x; h.y = (_Float16)v.y;
    h.z = (_Float16)v.z; h.w = (_Float16)v.w;
    *(half4*)(dst + i) = h;
}

// ---------- transpose leaf [NLEAF][NOUT] f32 -> leafT [NOUT][NLEAF] f16 ----------
__global__ void k_transpose_f16(const float* __restrict__ src,
                                _Float16* __restrict__ dst) {
    __shared__ _Float16 t[32][33];
    int l0 = blockIdx.x * 32, o0 = blockIdx.y * 32;
    int tx = threadIdx.x & 31, ty = threadIdx.x >> 5;  // 32 x 8
#pragma unroll
    for (int i = 0; i < 4; i++) {
        int l = l0 + ty + i * 8;
        t[ty + i * 8][tx] = (_Float16)src[(size_t)l * NOUT + o0 + tx];
    }
    __syncthreads();
#pragma unroll
    for (int i = 0; i < 4; i++) {
        int o = o0 + ty + i * 8;
        dst[(size_t)o * NLEAF + l0 + tx] = t[tx][ty + i * 8];
    }
}

// ====== 128x256 2-blocks/CU GEMM (C = A * B^T), 16x16x32 f16 MFMA ======
// R13 post-mortem: 256^2 tile = grid 256 = 1 block/CU; all 16 waves share ONE
// barrier group -> DS-burst/MFMA-burst alternation at every __syncthreads with
// nothing to fill the bubbles. This version keeps R13's per-wave geometry
// (64x64, R8-verified zero-conflict layout) and 4 waves/SIMD, but splits the
// CU into TWO independently-barriered blocks (m114 cross-group overlap):
//   tile 128x256, 8 waves (512 thr), BK=32, LDS 2buf x 24KB = 48KB,
//   __launch_bounds__(512,4) -> 2 blocks/CU; gate grid 16x32 = 512 = 2/CU.
// LDS layout per buf: A [128 rows][4 pos][8 halves] (8KB), B [256 rows][...]
// (16KB); chunk c of row r at pos c^((r>>1)&3) (both-sides, rule 21: source
// pre-swizzled, LDS dest linear, read same XOR -> measured 0 conflicts).
// Stage per K-tile: A 1 gload/thread, B 2 gloads/thread (rows +0,+128; the
// XOR term is invariant under +128). One __syncthreads per K-tile (implicit
// vmcnt drain is fine: T+1's stage was issued a full iteration earlier).
// EPILOGUE==1: C fp16 = sigmoid(acc + bias[col])   (gate GEMM)
// EPILOGUE==2: C fp16 partial at C + z*M*ldc       (leaf GEMM split-K)
// C/D layout (16x16): col = lane&15, row = (lane>>4)*4 + rj.
template <int EPILOGUE>
__launch_bounds__(512, 4)
__global__ void gemm128(const _Float16* __restrict__ A,
                        const _Float16* __restrict__ Bm,
                        const float* __restrict__ bias,
                        void* __restrict__ C,
                        int M, int N, int K, int ldc, int Klen) {
    __shared__ __align__(16) _Float16 As[2][128 * 32];
    __shared__ __align__(16) _Float16 Bs[2][256 * 32];
    const int tid  = threadIdx.x;
    const int lane = tid & 63;
    const int wid  = tid >> 6;       // 0..7
    const int wm   = wid >> 2;       // 0..1
    const int wn   = wid & 3;        // 0..3
    const int m0 = blockIdx.y * 128;
    const int n0 = blockIdx.x * 256;
    const int k0 = blockIdx.z * Klen;
    (void)N;

    floatx4 acc[4][4] = {};

    // ---- staging geometry: thread t covers A chunk (r=t>>2, p=t&3) and B
    // chunks (r, p) and (r+128, p); source chunk pre-swizzled c = p^((r>>1)&3).
    const int rr = tid >> 2;
    const int pp = tid & 3;
    const int cc = pp ^ ((tid >> 3) & 3);
    const _Float16* Abase  = A  + (size_t)(m0 + rr) * K + k0 + cc * 8;
    const _Float16* Bbase  = Bm + (size_t)(n0 + rr) * K + k0 + cc * 8;
    const _Float16* Bbase2 = Bbase + (size_t)128 * K;

    auto stage = [&](int bufx, int T) {
        gload_lds16(Abase  + T * 32, &As[bufx][tid * 8]);
        gload_lds16(Bbase  + T * 32, &Bs[bufx][tid * 8]);
        gload_lds16(Bbase2 + T * 32, &Bs[bufx][4096 + tid * 8]);
    };

    // ---- read geometry (R8-verified 2-way-free): fragment row = base + f*16
    // + (lane&15); pos = (lane>>4) ^ (((lane&15)>>1)&3), per-thread constant.
    const int l15 = lane & 15;
    const int l4  = lane >> 4;
    const int pos = (l4 ^ ((l15 >> 1) & 3)) * 8;
    const int ra  = wm * 64 + l15;   // + fi*16
    const int rb  = wn * 64 + l15;   // + fj*16

    const int NTt = Klen >> 5;

    // ---- prologue: stage tile 0 into buf 0
    stage(0, 0);
    __syncthreads();

    int buf = 0;
    for (int T = 0; T < NTt; ++T) {
        if (T + 1 < NTt) stage(buf ^ 1, T + 1);
        const _Float16* Ab = &As[buf][0];
        const _Float16* Bb = &Bs[buf][0];
        half8 af[4], bf[4];
#pragma unroll
        for (int fi = 0; fi < 4; fi++)
            af[fi] = *(const half8*)(Ab + (ra + fi * 16) * 32 + pos);
#pragma unroll
        for (int fj = 0; fj < 4; fj++)
            bf[fj] = *(const half8*)(Bb + (rb + fj * 16) * 32 + pos);
#pragma unroll
        for (int fi = 0; fi < 4; fi++)
#pragma unroll
            for (int fj = 0; fj < 4; fj++)
                acc[fi][fj] = __builtin_amdgcn_mfma_f32_16x16x32_f16(
                    af[fi], bf[fj], acc[fi][fj], 0, 0, 0);
        __syncthreads();  // drains next-tile stage + this tile's reads
        buf ^= 1;
    }

    // ---- epilogue: 16x16 C/D layout col=lane&15, row=(lane>>4)*4+rj
    _Float16* Cp = (_Float16*)C + (EPILOGUE == 2 ? (size_t)blockIdx.z * M * ldc : 0);
#pragma unroll
    for (int fi = 0; fi < 4; fi++)
#pragma unroll
        for (int fj = 0; fj < 4; fj++) {
            const int col = n0 + wn * 64 + fj * 16 + l15;
            float bb = 0.f;
            if (EPILOGUE == 1) bb = (col < NODES) ? bias[col] : 0.f;
#pragma unroll
            for (int rj = 0; rj < 4; rj++) {
                const int row = m0 + wm * 64 + fi * 16 + l4 * 4 + rj;
                float v = acc[fi][fj][rj];
                if (EPILOGUE == 1) {
                    float z = v + bb;
                    Cp[(size_t)row * ldc + col] = (_Float16)(1.f / (1.f + __expf(-z)));
                } else {
                    Cp[(size_t)row * ldc + col] = (_Float16)v;
                }
            }
        }
}

// ---------- reduce 4 fp16 partials -> f32 out ----------
__global__ void k_reduce4(const _Float16* __restrict__ part, float* __restrict__ out) {
    const size_t S = (size_t)BATCH * NOUT;
    size_t i = ((size_t)blockIdx.x * 256 + threadIdx.x) * 8;
    half8 a = *(const half8*)(part + i);
    half8 b = *(const half8*)(part + S + i);
    half8 c = *(const half8*)(part + 2 * S + i);
    half8 d = *(const half8*)(part + 3 * S + i);
    float4 lo, hi;
    lo.x = (float)a[0] + (float)b[0] + (float)c[0] + (float)d[0];
    lo.y = (float)a[1] + (float)b[1] + (float)c[1] + (float)d[1];
    lo.z = (float)a[2] + (float)b[2] + (float)c[2] + (float)d[2];
    lo.w = (float)a[3] + (float)b[3] + (float)c[3] + (float)d[3];
    hi.x = (float)a[4] + (float)b[4] + (float)c[4] + (float)d[4];
    hi.y = (float)a[5] + (float)b[5] + (float)c[5] + (float)d[5];
    hi.z = (float)a[6] + (float)b[6] + (float)c[6] + (float)d[6];
    hi.w = (float)a[7] + (float)b[7] + (float)c[7] + (float)d[7];
    *(float4*)(out + i) = lo;
    *(float4*)(out + i + 4) = hi;
}

// ---------- probs: per batch row, hierarchical tree-product expansion ----------
__global__ void k_probs(const _Float16* __restrict__ g,
                        _Float16* __restrict__ probs) {
    __shared__ float gs[NPAD];
    const int b = blockIdx.x;
    const _Float16* grow = g + (size_t)b * NPAD;
#pragma unroll
    for (int it = 0; it < 2; it++) {
        int i = threadIdx.x + it * 256;   // i in [0,512): 8 halves each
        half8 v = *(const half8*)(grow + i * 8);
#pragma unroll
        for (int j = 0; j < 8; j++) gs[i * 8 + j] = (float)v[j];
    }
    __syncthreads();
    const int t = threadIdx.x;  // subtree over leaves [t*16, t*16+16)
    float p = 1.f;
#pragma unroll
    for (int d = 0; d < 8; d++) {
        int node = (1 << d) - 1 + (t >> (8 - d));
        float gg = gs[node];
        int bit = (t >> (7 - d)) & 1;
        p *= bit ? gg : (1.f - gg);
    }
    float p9[2], p10[4], p11[8], p12[16];
    {
        float gg = gs[255 + t];
        p9[0] = p * (1.f - gg); p9[1] = p * gg;
    }
#pragma unroll
    for (int i = 0; i < 2; i++) {
        float gg = gs[511 + 2 * t + i];
        p10[2 * i] = p9[i] * (1.f - gg); p10[2 * i + 1] = p9[i] * gg;
    }
#pragma unroll
    for (int i = 0; i < 4; i++) {
        float gg = gs[1023 + 4 * t + i];
        p11[2 * i] = p10[i] * (1.f - gg); p11[2 * i + 1] = p10[i] * gg;
    }
#pragma unroll
    for (int i = 0; i < 8; i++) {
        float gg = gs[2047 + 8 * t + i];
        p12[2 * i] = p11[i] * (1.f - gg); p12[2 * i + 1] = p11[i] * gg;
    }
    half8 o0, o1;
#pragma unroll
    for (int j = 0; j < 8; j++) { o0[j] = (_Float16)p12[j]; o1[j] = (_Float16)p12[8 + j]; }
    _Float16* pr = probs + (size_t)b * NLEAF + t * 16;
    *(half8*)(pr) = o0;
    *(half8*)(pr + 8) = o1;
}

extern "C" void kernel_launch(void* const* d_in, const int* in_sizes, int n_in,
                              void* d_out, int out_size, void* d_ws, size_t ws_size,
                              hipStream_t stream) {
    (void)in_sizes; (void)n_in; (void)out_size; (void)ws_size;
    const float* x    = (const float*)d_in[0];
    const float* W    = (const float*)d_in[1];
    const float* bias = (const float*)d_in[2];
    const float* leaf = (const float*)d_in[3];
    float* out = (float*)d_out;

    // ws layout (halves). Long-lived first; partials alias the dead region.
    _Float16* base  = (_Float16*)d_ws;
    _Float16* leafT = base;                                   // [0,8) MB   live: transpose -> leaf GEMM
    _Float16* probs = base + (size_t)4 * 1024 * 1024;         // [8,40) MB  live: k_probs -> leaf GEMM
    _Float16* xh    = base + (size_t)20 * 1024 * 1024;        // [40,48) MB dead after gate GEMM
    _Float16* Wh    = base + (size_t)24 * 1024 * 1024;        // [48,56) MB dead after gate GEMM
    _Float16* g     = base + (size_t)28 * 1024 * 1024;        // [56,88) MB dead after k_probs
    _Float16* part  = xh;                                     // [40,72) MB written by leaf GEMM (after k_probs)

    k_f32_to_f16_pad<<<(BATCH * NIN / 4 + 255) / 256, 256, 0, stream>>>(
        x, xh, BATCH * NIN, BATCH * NIN);
    k_f32_to_f16_pad<<<(NPAD * NIN / 4 + 255) / 256, 256, 0, stream>>>(
        W, Wh, NPAD * NIN, NODES * NIN);
    k_transpose_f16<<<dim3(NLEAF / 32, NOUT / 32), 256, 0, stream>>>(leaf, leafT);

    gemm128<1><<<dim3(NPAD / 256, BATCH / 128, 1), 512, 0, stream>>>(
        xh, Wh, bias, (void*)g, BATCH, NPAD, NIN, NPAD, NIN);

    k_probs<<<BATCH, 256, 0, stream>>>(g, probs);

    gemm128<2><<<dim3(NOUT / 256, BATCH / 128, SPLITK), 512, 0, stream>>>(
        probs, leafT, nullptr, (void*)part, BATCH, NOUT, NLEAF, NOUT, NLEAF / SPLITK);

    k_reduce4<<<(BATCH * NOUT) / (256 * 8), 256, 0, stream>>>(part, out);
}

// Round 15
// 109.784 us; speedup vs baseline: 1.1730x; 1.1730x over previous
//
#include <hip/hip_runtime.h>
#include <hip/hip_bf16.h>
#include <hip/hip_fp16.h>

typedef _Float16 half8 __attribute__((ext_vector_type(8)));
typedef _Float16 half4 __attribute__((ext_vector_type(4)));
typedef float floatx4 __attribute__((ext_vector_type(4)));

#define BATCH   4096
#define NIN     1024
#define NODES   4095
#define NPAD    4096
#define NOUT    1024
#define NLEAF   4096
#define SPLITK  4

__device__ __forceinline__ void gload_lds16(const void* g, void* l) {
    __builtin_amdgcn_global_load_lds(
        (const __attribute__((address_space(1))) void*)g,
        (__attribute__((address_space(3))) void*)l, 16, 0, 0);
}

// ---------- fused preprocessing: x->f16, W->f16(pad), leaf->leafT f16 ----------
// One launch, 3 grid segments (saves 2 launch gaps; streams overlap).
__global__ void k_prep(const float* __restrict__ x, const float* __restrict__ W,
                       const float* __restrict__ leaf,
                       _Float16* __restrict__ xh, _Float16* __restrict__ Wh,
                       _Float16* __restrict__ leafT) {
    __shared__ _Float16 t[32][33];
    const int b = blockIdx.x;
    if (b < 4096) {              // x convert: 4M elems, 4/thread
        int i = (b * 256 + threadIdx.x) * 4;
        float4 v = *(const float4*)(x + i);
        half4 h;
        h.x = (_Float16)v.x; h.y = (_Float16)v.y;
        h.z = (_Float16)v.z; h.w = (_Float16)v.w;
        *(half4*)(xh + i) = h;
    } else if (b < 8192) {       // W convert with zero-pad to NPAD rows
        int i = ((b - 4096) * 256 + threadIdx.x) * 4;
        float4 v;
        if (i < NODES * NIN) v = *(const float4*)(W + i);
        else                 v = make_float4(0.f, 0.f, 0.f, 0.f);
        half4 h;
        h.x = (_Float16)v.x; h.y = (_Float16)v.y;
        h.z = (_Float16)v.z; h.w = (_Float16)v.w;
        *(half4*)(Wh + i) = h;
    } else {                     // leaf transpose: 4096 tiles of 32x32
        int tb = b - 8192;
        int l0 = (tb & 127) * 32, o0 = (tb >> 7) * 32;
        int tx = threadIdx.x & 31, ty = threadIdx.x >> 5;   // 32 x 8
#pragma unroll
        for (int i = 0; i < 4; i++) {
            int l = l0 + ty + i * 8;
            t[ty + i * 8][tx] = (_Float16)leaf[(size_t)l * NOUT + o0 + tx];
        }
        __syncthreads();
#pragma unroll
        for (int i = 0; i < 4; i++) {
            int o = o0 + ty + i * 8;
            leafT[(size_t)o * NLEAF + l0 + tx] = t[tx][ty + i * 8];
        }
    }
}

// ====== 256x256 16-wave TLP GEMM (C = A * B^T), 16x16x32 f16 MFMA ======
// R13 structure (best measured: 706 TF, conflicts 0) + micro-opt:
//  - K-loop unrolled x2 -> buf is a compile-time constant (LDS addresses fold
//    to immediates; kills runtime multi-dim indexing VALU).
//  - flattened LDS, per-thread precomputed offsets (aoff/boff/dsl).
// Geometry unchanged: 16 waves = 4/SIMD TLP, per-wave 64x64, one
// __syncthreads per K-tile, double-buffered LDS; R8-verified zero-conflict
// 64B-row layout, chunk c of row r at pos c^((r>>1)&3), both-sides (rule 21:
// pre-swizzled global source, linear LDS dest, read same XOR).
// LDS: As/Bs = [2 buf][2 half][2 ksub][128 rows x 4 pos x 8 halves] flattened.
// EPILOGUE==1: C fp16 = sigmoid(acc + bias[col])   (gate GEMM)
// EPILOGUE==2: C fp16 partial at C + z*M*ldc       (leaf GEMM split-K)
// C/D layout (16x16): col = lane&15, row = (lane>>4)*4 + rj.
template <int EPILOGUE>
__launch_bounds__(1024, 4)
__global__ void gemm256(const _Float16* __restrict__ A,
                        const _Float16* __restrict__ Bm,
                        const float* __restrict__ bias,
                        void* __restrict__ C,
                        int M, int N, int K, int ldc, int Klen) {
    __shared__ __align__(16) _Float16 As[2 * 16384];
    __shared__ __align__(16) _Float16 Bs[2 * 16384];
    const int tid  = threadIdx.x;
    const int lane = tid & 63;
    const int wid  = tid >> 6;       // 0..15
    const int wm   = wid >> 2;       // 0..3
    const int wn   = wid & 3;        // 0..3
    const int m0 = blockIdx.y * 256;
    const int n0 = blockIdx.x * 256;
    const int k0 = blockIdx.z * Klen;
    (void)N;

    floatx4 acc[4][4] = {};

    // ---- staging geometry: thread tid -> half h = tid>>9, row r = (tid>>2)&127,
    // pos p = tid&3; source chunk pre-swizzled c = p ^ ((r>>1)&3).
    const int hh = tid >> 9;
    const int rr = (tid >> 2) & 127;
    const int cc = (tid & 3) ^ ((tid >> 3) & 3);
    const _Float16* Abase = A  + (size_t)(m0 + hh * 128 + rr) * K + k0 + cc * 8;
    const _Float16* Bbase = Bm + (size_t)(n0 + hh * 128 + rr) * K + k0 + cc * 8;
    const int dsl = hh * 8192 + (tid & 511) * 8;   // dest offset within buf region

    auto stage = [&](int bufx, int T) {   // bufx is always a literal at call site
        const int d = bufx * 16384 + dsl;
        gload_lds16(Abase + T * 64,      &As[d]);
        gload_lds16(Abase + T * 64 + 32, &As[d + 4096]);
        gload_lds16(Bbase + T * 64,      &Bs[d]);
        gload_lds16(Bbase + T * 64 + 32, &Bs[d + 4096]);
    };

    // ---- read geometry (R8-verified 2-way-free): fragment row = base + f*16 +
    // (lane&15); pos = (lane>>4) ^ (((lane&15)>>1)&3), per-thread constant.
    const int l15 = lane & 15;
    const int l4  = lane >> 4;
    const int pos = (l4 ^ ((l15 >> 1) & 3)) * 8;
    const int aoff = ((wm & 1) * 64 + l15) * 32 + pos + (wm >> 1) * 8192;
    const int boff = ((wn & 1) * 64 + l15) * 32 + pos + (wn >> 1) * 8192;

    auto compute = [&](int bufx) {        // bufx literal at call site
#pragma unroll
        for (int s = 0; s < 2; s++) {
            const _Float16* Ab = &As[bufx * 16384 + s * 4096 + aoff];
            const _Float16* Bb = &Bs[bufx * 16384 + s * 4096 + boff];
            half8 af[4], bf[4];
#pragma unroll
            for (int fi = 0; fi < 4; fi++)
                af[fi] = *(const half8*)(Ab + fi * 512);
#pragma unroll
            for (int fj = 0; fj < 4; fj++)
                bf[fj] = *(const half8*)(Bb + fj * 512);
#pragma unroll
            for (int fi = 0; fi < 4; fi++)
#pragma unroll
                for (int fj = 0; fj < 4; fj++)
                    acc[fi][fj] = __builtin_amdgcn_mfma_f32_16x16x32_f16(
                        af[fi], bf[fj], acc[fi][fj], 0, 0, 0);
        }
    };

    const int NTt = Klen >> 6;           // 16 for both GEMMs (even)

    stage(0, 0);
    __syncthreads();
    for (int T = 0; T < NTt; T += 2) {
        if (T + 1 < NTt) stage(1, T + 1);
        compute(0);
        __syncthreads();
        if (T + 2 < NTt) stage(0, T + 2);
        if (T + 1 < NTt) compute(1);
        __syncthreads();
    }

    // ---- epilogue: 16x16 C/D layout col=lane&15, row=(lane>>4)*4+rj
    _Float16* Cp = (_Float16*)C + (EPILOGUE == 2 ? (size_t)blockIdx.z * M * ldc : 0);
#pragma unroll
    for (int fi = 0; fi < 4; fi++)
#pragma unroll
        for (int fj = 0; fj < 4; fj++) {
            const int col = n0 + wn * 64 + fj * 16 + l15;
            float bb = 0.f;
            if (EPILOGUE == 1) bb = (col < NODES) ? bias[col] : 0.f;
#pragma unroll
            for (int rj = 0; rj < 4; rj++) {
                const int row = m0 + wm * 64 + fi * 16 + l4 * 4 + rj;
                float v = acc[fi][fj][rj];
                if (EPILOGUE == 1) {
                    float z = v + bb;
                    Cp[(size_t)row * ldc + col] = (_Float16)(1.f / (1.f + __expf(-z)));
                } else {
                    Cp[(size_t)row * ldc + col] = (_Float16)v;
                }
            }
        }
}

// ---------- reduce 4 fp16 partials -> f32 out ----------
__global__ void k_reduce4(const _Float16* __restrict__ part, float* __restrict__ out) {
    const size_t S = (size_t)BATCH * NOUT;
    size_t i = ((size_t)blockIdx.x * 256 + threadIdx.x) * 8;
    half8 a = *(const half8*)(part + i);
    half8 b = *(const half8*)(part + S + i);
    half8 c = *(const half8*)(part + 2 * S + i);
    half8 d = *(const half8*)(part + 3 * S + i);
    float4 lo, hi;
    lo.x = (float)a[0] + (float)b[0] + (float)c[0] + (float)d[0];
    lo.y = (float)a[1] + (float)b[1] + (float)c[1] + (float)d[1];
    lo.z = (float)a[2] + (float)b[2] + (float)c[2] + (float)d[2];
    lo.w = (float)a[3] + (float)b[3] + (float)c[3] + (float)d[3];
    hi.x = (float)a[4] + (float)b[4] + (float)c[4] + (float)d[4];
    hi.y = (float)a[5] + (float)b[5] + (float)c[5] + (float)d[5];
    hi.z = (float)a[6] + (float)b[6] + (float)c[6] + (float)d[6];
    hi.w = (float)a[7] + (float)b[7] + (float)c[7] + (float)d[7];
    *(float4*)(out + i) = lo;
    *(float4*)(out + i + 4) = hi;
}

// ---------- probs: per batch row, hierarchical tree-product expansion ----------
__global__ void k_probs(const _Float16* __restrict__ g,
                        _Float16* __restrict__ probs) {
    __shared__ float gs[NPAD];
    const int b = blockIdx.x;
    const _Float16* grow = g + (size_t)b * NPAD;
#pragma unroll
    for (int it = 0; it < 2; it++) {
        int i = threadIdx.x + it * 256;   // i in [0,512): 8 halves each
        half8 v = *(const half8*)(grow + i * 8);
#pragma unroll
        for (int j = 0; j < 8; j++) gs[i * 8 + j] = (float)v[j];
    }
    __syncthreads();
    const int t = threadIdx.x;  // subtree over leaves [t*16, t*16+16)
    float p = 1.f;
#pragma unroll
    for (int d = 0; d < 8; d++) {
        int node = (1 << d) - 1 + (t >> (8 - d));
        float gg = gs[node];
        int bit = (t >> (7 - d)) & 1;
        p *= bit ? gg : (1.f - gg);
    }
    float p9[2], p10[4], p11[8], p12[16];
    {
        float gg = gs[255 + t];
        p9[0] = p * (1.f - gg); p9[1] = p * gg;
    }
#pragma unroll
    for (int i = 0; i < 2; i++) {
        float gg = gs[511 + 2 * t + i];
        p10[2 * i] = p9[i] * (1.f - gg); p10[2 * i + 1] = p9[i] * gg;
    }
#pragma unroll
    for (int i = 0; i < 4; i++) {
        float gg = gs[1023 + 4 * t + i];
        p11[2 * i] = p10[i] * (1.f - gg); p11[2 * i + 1] = p10[i] * gg;
    }
#pragma unroll
    for (int i = 0; i < 8; i++) {
        float gg = gs[2047 + 8 * t + i];
        p12[2 * i] = p11[i] * (1.f - gg); p12[2 * i + 1] = p11[i] * gg;
    }
    half8 o0, o1;
#pragma unroll
    for (int j = 0; j < 8; j++) { o0[j] = (_Float16)p12[j]; o1[j] = (_Float16)p12[8 + j]; }
    _Float16* pr = probs + (size_t)b * NLEAF + t * 16;
    *(half8*)(pr) = o0;
    *(half8*)(pr + 8) = o1;
}

extern "C" void kernel_launch(void* const* d_in, const int* in_sizes, int n_in,
                              void* d_out, int out_size, void* d_ws, size_t ws_size,
                              hipStream_t stream) {
    (void)in_sizes; (void)n_in; (void)out_size; (void)ws_size;
    const float* x    = (const float*)d_in[0];
    const float* W    = (const float*)d_in[1];
    const float* bias = (const float*)d_in[2];
    const float* leaf = (const float*)d_in[3];
    float* out = (float*)d_out;

    // ws layout (halves). Long-lived first; partials alias the dead region.
    _Float16* base  = (_Float16*)d_ws;
    _Float16* leafT = base;                                   // [0,8) MB   live: prep -> leaf GEMM
    _Float16* probs = base + (size_t)4 * 1024 * 1024;         // [8,40) MB  live: k_probs -> leaf GEMM
    _Float16* xh    = base + (size_t)20 * 1024 * 1024;        // [40,48) MB dead after gate GEMM
    _Float16* Wh    = base + (size_t)24 * 1024 * 1024;        // [48,56) MB dead after gate GEMM
    _Float16* g     = base + (size_t)28 * 1024 * 1024;        // [56,88) MB dead after k_probs
    _Float16* part  = xh;                                     // [40,72) MB written by leaf GEMM (after k_probs)

    k_prep<<<12288, 256, 0, stream>>>(x, W, leaf, xh, Wh, leafT);

    gemm256<1><<<dim3(NPAD / 256, BATCH / 256, 1), 1024, 0, stream>>>(
        xh, Wh, bias, (void*)g, BATCH, NPAD, NIN, NPAD, NIN);

    k_probs<<<BATCH, 256, 0, stream>>>(g, probs);

    gemm256<2><<<dim3(NOUT / 256, BATCH / 256, SPLITK), 1024, 0, stream>>>(
        probs, leafT, nullptr, (void*)part, BATCH, NOUT, NLEAF, NOUT, NLEAF / SPLITK);

    k_reduce4<<<(BATCH * NOUT) / (256 * 8), 256, 0, stream>>>(part, out);
}